// Round 1
// 762.019 us; speedup vs baseline: 1.2855x; 1.2855x over previous
//
#include <hip/hip_runtime.h>
#include <hip/hip_bf16.h>
#include <stdint.h>

typedef __hip_bfloat16 bf16;
typedef __attribute__((ext_vector_type(8))) __bf16 bf16x8;
typedef __attribute__((ext_vector_type(4))) float f32x4;

#define D_MODEL 1024
#define NHEAD   16
#define HDIM    64
#define DFF     4096
#define BATCH   16
#define SEQ     512
#define MROWS   (BATCH*SEQ)   // 8192

__device__ __forceinline__ float b2f_bits(unsigned short u) {
    return __uint_as_float(((unsigned)u) << 16);
}
__device__ __forceinline__ bf16 f2b(float v) { return __float2bfloat16(v); }
__device__ __forceinline__ unsigned short f2b_bits(float v) {
    bf16 t = __float2bfloat16(v);
    return *(unsigned short*)&t;
}

// ---------------------------------------------------------------------------
// fp32 -> bf16 weight conversion (n multiple of 4; grid covers exactly n/4)
// ---------------------------------------------------------------------------
__global__ __launch_bounds__(256)
void cvt_kernel(const float* __restrict__ in, bf16* __restrict__ out, int n)
{
    int i = (blockIdx.x * 256 + threadIdx.x) * 4;
    if (i >= n) return;
    float4 f = *(const float4*)(in + i);
    ushort4 o;
    o.x = f2b_bits(f.x); o.y = f2b_bits(f.y);
    o.z = f2b_bits(f.z); o.w = f2b_bits(f.w);
    *(ushort4*)((unsigned short*)out + i) = o;
}

// ---------------------------------------------------------------------------
// LayerNorm: fp32 in, bf16 out. One block (256 threads) per row of 1024.
// ---------------------------------------------------------------------------
__global__ __launch_bounds__(256)
void ln_kernel(const float* __restrict__ xin, const float* __restrict__ w,
               const float* __restrict__ b, bf16* __restrict__ out)
{
    int row  = blockIdx.x;
    int t    = threadIdx.x;
    int lane = t & 63, wv = t >> 6;
    int col  = t * 4;

    float4 f = *(const float4*)(xin + (size_t)row * D_MODEL + col);
    float v[4] = {f.x, f.y, f.z, f.w};

    float s  = v[0] + v[1] + v[2] + v[3];
    float ss = v[0]*v[0] + v[1]*v[1] + v[2]*v[2] + v[3]*v[3];
    #pragma unroll
    for (int m = 1; m < 64; m <<= 1) {
        s  += __shfl_xor(s,  m, 64);
        ss += __shfl_xor(ss, m, 64);
    }
    __shared__ float rs0[4], rs1[4];
    if (lane == 0) { rs0[wv] = s; rs1[wv] = ss; }
    __syncthreads();
    s  = rs0[0] + rs0[1] + rs0[2] + rs0[3];
    ss = rs1[0] + rs1[1] + rs1[2] + rs1[3];

    float mu  = s * (1.0f / D_MODEL);
    float var = ss * (1.0f / D_MODEL) - mu * mu;
    float rs  = rsqrtf(var + 1e-5f);

    float4 wf = *(const float4*)(w + col);
    float4 bf = *(const float4*)(b + col);
    ushort4 o;
    o.x = f2b_bits((v[0]-mu)*rs*wf.x + bf.x);
    o.y = f2b_bits((v[1]-mu)*rs*wf.y + bf.y);
    o.z = f2b_bits((v[2]-mu)*rs*wf.z + bf.z);
    o.w = f2b_bits((v[3]-mu)*rs*wf.w + bf.w);
    *(ushort4*)((unsigned short*)out + (size_t)row * D_MODEL + col) = o;
}

// ---------------------------------------------------------------------------
// MFMA GEMM: C[M,N] = A[M,K] * Bw[N,K]^T + bias (fp32). Epilogues:
//   EPI 0: bias -> out            EPI 1: bias + exact GELU -> out
//   EPI 2: bias + fp32 residual -> out
//   EPI 3: bias -> scatter bf16 Q (b,h,s,e) / K (b,h,s,e) / VT (b,h,e,s)
// OUT_B16: store bf16 (internal buffers) vs fp32 (x1 / d_out).
// 128x128 tile, 256 threads (4 waves 2x2), wave = 4x4 mfma_f32_16x16x32_bf16.
// C/D mapping (m89/m91 verified): col = lane&15, row = (lane>>4)*4 + reg.
// M,N multiples of 128; K multiple of 32.
// ---------------------------------------------------------------------------
template<int EPI, bool OUT_B16>
__global__ __launch_bounds__(256)
void gemm_bt(const bf16* __restrict__ A, const bf16* __restrict__ Bw,
             const float* __restrict__ bias, const float* __restrict__ resid,
             void* __restrict__ Cout, bf16* __restrict__ qb,
             bf16* __restrict__ ktb, bf16* __restrict__ vb,
             int M, int N, int K)
{
    int t    = threadIdx.x;
    int lane = t & 63, w = t >> 6;
    int wm   = w & 1,  wn = w >> 1;
    int q    = lane >> 4, r = lane & 15;
    int mb   = blockIdx.y * 128, nb = blockIdx.x * 128;

    __shared__ __bf16 As[128 * 32];
    __shared__ __bf16 Bs[128 * 32];

    f32x4 acc[4][4] = {};

    const unsigned short* Ag = (const unsigned short*)A + (size_t)mb * K;
    const unsigned short* Bg = (const unsigned short*)Bw + (size_t)nb * K;

    int ar0 = t >> 2,         ac0 = (t & 3) << 3;
    int ar1 = (t + 256) >> 2, ac1 = ((t + 256) & 3) << 3;

    for (int k0 = 0; k0 < K; k0 += 32) {
        int4 a0 = *(const int4*)(Ag + (size_t)ar0 * K + k0 + ac0);
        int4 a1 = *(const int4*)(Ag + (size_t)ar1 * K + k0 + ac1);
        int4 b0 = *(const int4*)(Bg + (size_t)ar0 * K + k0 + ac0);
        int4 b1 = *(const int4*)(Bg + (size_t)ar1 * K + k0 + ac1);
        __syncthreads();
        *(int4*)(As + ar0 * 32 + ac0) = a0;
        *(int4*)(As + ar1 * 32 + ac1) = a1;
        *(int4*)(Bs + ar0 * 32 + ac0) = b0;
        *(int4*)(Bs + ar1 * 32 + ac1) = b1;
        __syncthreads();

        bf16x8 af[4], bfr[4];
        #pragma unroll
        for (int i = 0; i < 4; i++)
            af[i] = *(const bf16x8*)(As + (wm * 64 + i * 16 + r) * 32 + q * 8);
        #pragma unroll
        for (int j = 0; j < 4; j++)
            bfr[j] = *(const bf16x8*)(Bs + (wn * 64 + j * 16 + r) * 32 + q * 8);
        #pragma unroll
        for (int i = 0; i < 4; i++)
            #pragma unroll
            for (int j = 0; j < 4; j++)
                acc[i][j] = __builtin_amdgcn_mfma_f32_16x16x32_bf16(af[i], bfr[j], acc[i][j], 0, 0, 0);
    }

    #pragma unroll
    for (int j = 0; j < 4; j++) {
        int n = nb + wn * 64 + j * 16 + r;
        float bv = bias[n];
        #pragma unroll
        for (int i = 0; i < 4; i++) {
            int mbase = mb + wm * 64 + i * 16 + q * 4;
            #pragma unroll
            for (int rr = 0; rr < 4; rr++) {
                int m = mbase + rr;
                float v = acc[i][j][rr] + bv;
                if (EPI == 1) v = 0.5f * v * (1.0f + erff(v * 0.70710678118654752f));
                if (EPI == 2) v += resid[(size_t)m * N + n];
                if (EPI == 3) {
                    int sect = n >> 10;
                    int h = (n >> 6) & 15;
                    int e = n & 63;
                    int bi = m >> 9, s = m & 511;
                    size_t bh = (size_t)bi * NHEAD + h;
                    bf16 val = f2b(v);
                    if (sect == 0)      qb[((bh * SEQ + s) << 6) + e] = val;
                    else if (sect == 1) ktb[((bh * SEQ + s) << 6) + e] = val;  // K rows
                    else                vb[((bh * HDIM + e) << 9) + s] = val;  // V^T
                } else {
                    if (OUT_B16) ((bf16*)Cout)[(size_t)m * N + n] = f2b(v);
                    else         ((float*)Cout)[(size_t)m * N + n] = v;
                }
            }
        }
    }
}

// ---------------------------------------------------------------------------
// MFMA attention. Grid (8 q-tiles, 256 bh), 256 thr = 4 waves.
// Each wave: 16 q-rows x 512 keys. Q,K (b,h,s,64); VT (b,h,64,s); all bf16.
// scores = QK^T * 0.125 + rel_bias (rel-bias row staged in LDS);
// row max/sum via 16-lane shfl reduce; P = exp(s-m) packed bf16 into
// XOR-swizzled LDS (byte ^= (row&7)<<4 kills the 1024B-stride bank conflict);
// out = (P @ VT^T) * (1/sum), written to (b,s,h*64+e) bf16.
// A-frag layout: lane holds A[row=lane&15][k=(lane>>4)*8..+7]; C/D:
// col=lane&15, row=(lane>>4)*4+reg (m89/m91 verified).
// ---------------------------------------------------------------------------
__global__ __launch_bounds__(256, 2)
void attn_mfma(const bf16* __restrict__ Q, const bf16* __restrict__ K,
               const bf16* __restrict__ VT, const float* __restrict__ relb,
               bf16* __restrict__ out)
{
    int bh = blockIdx.y;
    int b  = bh >> 4, h = bh & 15;
    int q0 = blockIdx.x * 64;
    int t = threadIdx.x, lane = t & 63, w = t >> 6;
    int l15 = lane & 15, l4 = lane >> 4;

    __shared__ __bf16 Pls[64 * 512];   // 64 KiB, swizzled
    __shared__ float  rbs[1024];       // rel-bias row for this head

    const float* rb = relb + (size_t)h * (2 * SEQ - 1);
    for (int i = t; i < 2 * SEQ - 1; i += 256) rbs[i] = rb[i];
    __syncthreads();

    // ---- QK^T: 32 key-tiles of 16, 2 MFMAs each ----
    const unsigned short* Qp = (const unsigned short*)Q
        + (((size_t)bh * SEQ + q0 + w * 16 + l15) << 6) + l4 * 8;
    bf16x8 qf0 = *(const bf16x8*)Qp;
    bf16x8 qf1 = *(const bf16x8*)(Qp + 32);

    const unsigned short* Kp = (const unsigned short*)K
        + (((size_t)bh * SEQ + l15) << 6) + l4 * 8;

    f32x4 sc[32];
    #pragma unroll
    for (int kt = 0; kt < 32; kt++) {
        const unsigned short* kp = Kp + ((size_t)kt << 10);  // 16 rows * 64
        bf16x8 kf0 = *(const bf16x8*)kp;
        bf16x8 kf1 = *(const bf16x8*)(kp + 32);
        f32x4 a = {};
        a = __builtin_amdgcn_mfma_f32_16x16x32_bf16(qf0, kf0, a, 0, 0, 0);
        a = __builtin_amdgcn_mfma_f32_16x16x32_bf16(qf1, kf1, a, 0, 0, 0);
        sc[kt] = a;
    }

    // ---- scale + bias + row max ----
    int qbase = q0 + w * 16 + l4 * 4;          // + reg = this lane's rows
    float mx[4] = {-1e30f, -1e30f, -1e30f, -1e30f};
    #pragma unroll
    for (int kt = 0; kt < 32; kt++) {
        int relbase = qbase - (kt * 16 + l15) + (SEQ - 1);
        #pragma unroll
        for (int reg = 0; reg < 4; reg++) {
            float v = sc[kt][reg] * 0.125f + rbs[relbase + reg];
            sc[kt][reg] = v;
            mx[reg] = fmaxf(mx[reg], v);
        }
    }
    #pragma unroll
    for (int m = 1; m < 16; m <<= 1)
        #pragma unroll
        for (int reg = 0; reg < 4; reg++)
            mx[reg] = fmaxf(mx[reg], __shfl_xor(mx[reg], m, 64));

    // ---- exp, sum, pack bf16 pairs -> swizzled LDS ----
    char* Pb = (char*)Pls;
    float sum[4] = {0.f, 0.f, 0.f, 0.f};
    #pragma unroll
    for (int kt = 0; kt < 32; kt++) {
        #pragma unroll
        for (int reg = 0; reg < 4; reg++) {
            float p = __expf(sc[kt][reg] - mx[reg]);
            sum[reg] += p;
            float o = __shfl_xor(p, 1, 64);          // partner column
            unsigned lo = f2b_bits((lane & 1) ? o : p);
            unsigned hi = f2b_bits((lane & 1) ? p : o);
            unsigned pk = lo | (hi << 16);
            if ((lane & 1) == (reg >> 1)) {          // even lanes: reg 0,1; odd: 2,3
                int row  = w * 16 + l4 * 4 + reg;
                int byte = (row << 10) + (((kt << 4) + (l15 & ~1)) << 1);
                byte ^= (row & 7) << 4;
                *(unsigned*)(Pb + byte) = pk;
            }
        }
    }
    #pragma unroll
    for (int m = 1; m < 16; m <<= 1)
        #pragma unroll
        for (int reg = 0; reg < 4; reg++)
            sum[reg] += __shfl_xor(sum[reg], m, 64);
    float rcp[4];
    #pragma unroll
    for (int reg = 0; reg < 4; reg++) rcp[reg] = 1.0f / sum[reg];

    // ---- P @ V^T (wave-private LDS rows; compiler orders ds write->read) ----
    const unsigned short* Vp = (const unsigned short*)VT
        + ((size_t)bh << 15) + ((size_t)l15 << 9) + l4 * 8;
    int prowbase = (w * 16 + l15) << 10;
    int pswz     = ((w * 16 + l15) & 7) << 4;
    f32x4 oacc[4] = {};
    #pragma unroll
    for (int kt2 = 0; kt2 < 16; kt2++) {
        int byte = prowbase + kt2 * 64 + l4 * 16;
        byte ^= pswz;
        bf16x8 pf = *(const bf16x8*)(Pb + byte);
        #pragma unroll
        for (int et = 0; et < 4; et++) {
            bf16x8 vf = *(const bf16x8*)(Vp + ((size_t)et << 13) + kt2 * 32);
            oacc[et] = __builtin_amdgcn_mfma_f32_16x16x32_bf16(pf, vf, oacc[et], 0, 0, 0);
        }
    }

    bf16* op = out + (size_t)(b * SEQ + q0 + w * 16 + l4 * 4) * D_MODEL
             + h * HDIM + l15;
    #pragma unroll
    for (int et = 0; et < 4; et++)
        #pragma unroll
        for (int reg = 0; reg < 4; reg++)
            op[(size_t)reg * D_MODEL + et * 16] = f2b(oacc[et][reg] * rcp[reg]);
}

// ---------------------------------------------------------------------------
// Launch. Inputs fp32 (dict order), OUTPUT fp32 (reference dtype).
// ws peak 105 MiB:
//   [1,7)     wqkv_b     [7,9) wo_b
//   [9,25)    xn -> xn2  (sequential liveness)
//   [25,41)   Q  \
//   [41,57)   K   } -> x1 fp32 [25,57) after attention
//   [57,65)   w1_b       [65,73) w2_b
//   [73,105)  hid bf16 4096x4096 chunk
// d_out (32 MiB fp32) doubles as scratch before final writes:
//   VT bf16 = d_out[0,16M), att bf16 = d_out[16M,32M)
// ---------------------------------------------------------------------------
extern "C" void kernel_launch(void* const* d_in, const int* in_sizes, int n_in,
                              void* d_out, int out_size, void* d_ws, size_t ws_size,
                              hipStream_t stream)
{
    const float* x    = (const float*)d_in[0];
    const float* wqkv = (const float*)d_in[1];
    const float* bqkv = (const float*)d_in[2];
    const float* wo   = (const float*)d_in[3];
    const float* bo   = (const float*)d_in[4];
    const float* relb = (const float*)d_in[5];
    const float* w1   = (const float*)d_in[6];
    const float* b1   = (const float*)d_in[7];
    const float* w2   = (const float*)d_in[8];
    const float* b2   = (const float*)d_in[9];
    const float* ln1w = (const float*)d_in[10];
    const float* ln1b = (const float*)d_in[11];
    const float* ln2w = (const float*)d_in[12];
    const float* ln2b = (const float*)d_in[13];

    char* ws = (char*)d_ws;
    const size_t MB = 1048576;
    bf16*  wqkv_b = (bf16*)(ws + 1 * MB);
    bf16*  wo_b   = (bf16*)(ws + 7 * MB);
    bf16*  xn     = (bf16*)(ws + 9 * MB);
    bf16*  Qb     = (bf16*)(ws + 25 * MB);
    bf16*  Kb     = (bf16*)(ws + 41 * MB);
    float* x1     = (float*)(ws + 25 * MB);  // over dead Q+K, 32 MiB
    bf16*  w1_b   = (bf16*)(ws + 57 * MB);
    bf16*  w2_b   = (bf16*)(ws + 65 * MB);
    bf16*  xn2    = (bf16*)(ws + 9 * MB);    // over dead xn
    bf16*  hid    = (bf16*)(ws + 73 * MB);   // 4096x4096 bf16 chunk
    bf16*  VT     = (bf16*)d_out;                       // d_out[0,16M)
    bf16*  att    = (bf16*)((char*)d_out + 16 * MB);    // d_out[16M,32M)
    float* out    = (float*)d_out;

    // 1. all weights fp32 -> bf16
    cvt_kernel<<<3072, 256, 0, stream>>>(wqkv, wqkv_b, 3 * D_MODEL * D_MODEL);
    cvt_kernel<<<1024, 256, 0, stream>>>(wo,   wo_b,   D_MODEL * D_MODEL);
    cvt_kernel<<<4096, 256, 0, stream>>>(w1,   w1_b,   DFF * D_MODEL);
    cvt_kernel<<<4096, 256, 0, stream>>>(w2,   w2_b,   D_MODEL * DFF);
    // 2. xn = LN1(x)
    ln_kernel<<<MROWS, 256, 0, stream>>>(x, ln1w, ln1b, xn);
    // 3. qkv projection scattered into Q / K / VT(=d_out scratch)
    gemm_bt<3,true><<<dim3(24, 64), 256, 0, stream>>>(xn, wqkv_b, bqkv, nullptr,
        nullptr, Qb, Kb, VT, MROWS, 3 * D_MODEL, D_MODEL);
    // 4. MFMA attention -> att (d_out scratch, bf16)
    attn_mfma<<<dim3(8, 256), 256, 0, stream>>>(Qb, Kb, VT, relb, att);
    // 5. x1 = x + att @ Wo^T + bo   (fp32, over dead Q+K)
    gemm_bt<2,false><<<dim3(8, 64), 256, 0, stream>>>(att, wo_b, bo, x,
        x1, nullptr, nullptr, nullptr, MROWS, D_MODEL, D_MODEL);
    // 6. xn2 = LN2(x1)   (over dead xn)
    ln_kernel<<<MROWS, 256, 0, stream>>>(x1, ln2w, ln2b, xn2);
    // 7/8. FFN in 2 chunks of 4096 rows; final writes fp32 into d_out
    for (int c = 0; c < 2; c++) {
        const bf16*  xc = xn2 + (size_t)c * 4096 * D_MODEL;
        const float* rc = x1  + (size_t)c * 4096 * D_MODEL;
        float*       oc = out + (size_t)c * 4096 * D_MODEL;
        gemm_bt<1,true><<<dim3(32, 32), 256, 0, stream>>>(xc, w1_b, b1, nullptr,
            hid, nullptr, nullptr, nullptr, 4096, DFF, D_MODEL);
        gemm_bt<2,false><<<dim3(8, 32), 256, 0, stream>>>(hid, w2_b, b2, rc,
            oc, nullptr, nullptr, nullptr, 4096, D_MODEL, DFF);
    }
}